// Round 1
// baseline (342.178 us; speedup 1.0000x reference)
//
#include <hip/hip_runtime.h>

// Performer causal linear attention, fp32, MI355X.
// b=2 h=8 n=4096 d=64 r=256 e=64, chunk=64.
// Stages: feat (q/k -> feature-map GEMM + stabilizers) -> chunk sums ->
// chunk prefix -> masked intra-chunk scores + denominator -> output.

#define BHN 65536          // b*h*n rows
#define NSEQ 4096
#define RDIM 256
#define DDIM 64
#define EDIM 64
#define CHK 64
#define NCHK 64
#define NBC 1024           // BH*NCHK

#define KEPS 1e-4f
#define AEPS 1e-6f
#define NORMIZER 0.35355339059327373f   // 64^-0.25
#define RATIO 0.0625f                   // 256^-0.5

// workspace offsets (floats). total ~54.9M floats (~210 MB)
#define QP_OFF   0ull
#define KD_OFF   16777216ull
#define S_OFF    33554432ull
#define Z_OFF    50331648ull
#define A_OFF    50593792ull
#define DINV_OFF 54788096ull
#define KMAX_OFF 54853632ull

__device__ __forceinline__ unsigned fenc(float f) {
  unsigned u = __float_as_uint(f);
  return (u & 0x80000000u) ? ~u : (u | 0x80000000u);
}
__device__ __forceinline__ float fdec(unsigned e) {
  unsigned u = (e & 0x80000000u) ? (e ^ 0x80000000u) : ~e;
  return __uint_as_float(u);
}

// ---------------------------------------------------------------------------
// K1: feature GEMM. blocks 0..1023 -> q rows, 1024..2047 -> k rows.
// Each block: 64 rows x 256 cols, P staged in LDS in 2 column-halves.
// q: apply per-row stab + exp -> qp.   k: store dash-diag, atomicMax global max.
__global__ __launch_bounds__(256) void feat_kernel(
    const float* __restrict__ Q, const float* __restrict__ K,
    const float* __restrict__ P, float* __restrict__ qp,
    float* __restrict__ kd, unsigned int* __restrict__ kmax)
{
  __shared__ float xs[64 * 68];    // [k][row] transposed, pad 68 (16B-aligned rows)
  __shared__ float ps[64 * 132];   // [k][col] for one 128-col half, pad 132
  __shared__ float red[4];

  int bid = blockIdx.x;
  int tid = threadIdx.x;
  bool isK = bid >= 1024;
  const float* X = isK ? K : Q;
  int rowbase = (isK ? bid - 1024 : bid) * 64;

  // load x tile transposed: coalesced global, LDS write stride 68
  #pragma unroll
  for (int p = 0; p < 16; ++p) {
    int idx = tid + p * 256;
    int rl = idx >> 6, kl = idx & 63;
    xs[kl * 68 + rl] = X[(size_t)(rowbase + rl) * 64 + kl];
  }

  int cg = tid & 31;   // 32 col-groups * 4 cols = 128 cols per pass
  int rg = tid >> 5;   // 8 row-groups * 8 rows

  float dash[2][8][4];

  #pragma unroll
  for (int pass = 0; pass < 2; ++pass) {
    __syncthreads();
    // load P columns [pass*128, pass*128+128) transposed into LDS
    #pragma unroll
    for (int p = 0; p < 32; ++p) {
      int idx = tid + p * 256;       // 8192 elements
      int col = idx >> 6, kl = idx & 63;
      ps[kl * 132 + col] = P[(size_t)(pass * 128 + col) * 64 + kl];
    }
    __syncthreads();

    float acc[32];
    #pragma unroll
    for (int t2 = 0; t2 < 32; ++t2) acc[t2] = 0.f;

    for (int kl = 0; kl < 64; ++kl) {
      float4 pv  = *(const float4*)&ps[kl * 132 + cg * 4];
      float4 xv0 = *(const float4*)&xs[kl * 68 + rg * 8];
      float4 xv1 = *(const float4*)&xs[kl * 68 + rg * 8 + 4];
      float xr[8] = {xv0.x, xv0.y, xv0.z, xv0.w, xv1.x, xv1.y, xv1.z, xv1.w};
      #pragma unroll
      for (int rr = 0; rr < 8; ++rr) {
        acc[rr * 4 + 0] += xr[rr] * pv.x;
        acc[rr * 4 + 1] += xr[rr] * pv.y;
        acc[rr * 4 + 2] += xr[rr] * pv.z;
        acc[rr * 4 + 3] += xr[rr] * pv.w;
      }
    }
    #pragma unroll
    for (int rr = 0; rr < 8; ++rr)
      #pragma unroll
      for (int cc = 0; cc < 4; ++cc)
        dash[pass][rr][cc] = NORMIZER * acc[rr * 4 + cc];
  }

  // per-row diag = 0.5 * n^2 * sumsq = sumsq/16 ; half-wave (32-lane) reduce
  float diag[8];
  #pragma unroll
  for (int rr = 0; rr < 8; ++rr) {
    int row = rg * 8 + rr;
    float a = xs[cg * 68 + row];          // k = cg
    float b = xs[(cg + 32) * 68 + row];   // k = cg+32
    float p = a * a + b * b;
    #pragma unroll
    for (int m = 1; m < 32; m <<= 1) p += __shfl_xor(p, m, 64);
    diag[rr] = 0.0625f * p;
  }

  if (!isK) {
    #pragma unroll
    for (int rr = 0; rr < 8; ++rr) {
      float mx = -3.0e38f;
      #pragma unroll
      for (int pass = 0; pass < 2; ++pass)
        #pragma unroll
        for (int cc = 0; cc < 4; ++cc)
          mx = fmaxf(mx, dash[pass][rr][cc]);
      #pragma unroll
      for (int m = 1; m < 32; m <<= 1) mx = fmaxf(mx, __shfl_xor(mx, m, 64));
      int row = rowbase + rg * 8 + rr;
      #pragma unroll
      for (int pass = 0; pass < 2; ++pass) {
        float4 o;
        o.x = RATIO * (__expf(dash[pass][rr][0] - diag[rr] - mx) + KEPS);
        o.y = RATIO * (__expf(dash[pass][rr][1] - diag[rr] - mx) + KEPS);
        o.z = RATIO * (__expf(dash[pass][rr][2] - diag[rr] - mx) + KEPS);
        o.w = RATIO * (__expf(dash[pass][rr][3] - diag[rr] - mx) + KEPS);
        *(float4*)&qp[(size_t)row * 256 + pass * 128 + cg * 4] = o;
      }
    }
  } else {
    float bmax = -3.0e38f;
    #pragma unroll
    for (int rr = 0; rr < 8; ++rr) {
      int row = rowbase + rg * 8 + rr;
      #pragma unroll
      for (int pass = 0; pass < 2; ++pass) {
        float4 o;
        o.x = dash[pass][rr][0] - diag[rr];
        o.y = dash[pass][rr][1] - diag[rr];
        o.z = dash[pass][rr][2] - diag[rr];
        o.w = dash[pass][rr][3] - diag[rr];
        bmax = fmaxf(bmax, fmaxf(fmaxf(dash[pass][rr][0], dash[pass][rr][1]),
                                 fmaxf(dash[pass][rr][2], dash[pass][rr][3])));
        *(float4*)&kd[(size_t)row * 256 + pass * 128 + cg * 4] = o;
      }
    }
    #pragma unroll
    for (int m = 1; m < 64; m <<= 1) bmax = fmaxf(bmax, __shfl_xor(bmax, m, 64));
    if ((tid & 63) == 0) red[tid >> 6] = bmax;
    __syncthreads();
    if (tid == 0) {
      float m4 = fmaxf(fmaxf(red[0], red[1]), fmaxf(red[2], red[3]));
      atomicMax(kmax, fenc(m4));
    }
  }
}

// ---------------------------------------------------------------------------
// K2: per-chunk sums. block = (bh, c). thread j owns S_c row j (64 accs) + Z_c[j].
// kp computed inline: ratio*(exp(kd - kmax) + eps)
__global__ __launch_bounds__(256) void chunksum_kernel(
    const float* __restrict__ kd, const float* __restrict__ V,
    const unsigned int* __restrict__ kmax,
    float* __restrict__ S, float* __restrict__ Z)
{
  __shared__ float vs[4096];
  int bc = blockIdx.x, tid = threadIdx.x;
  float m = fdec(*kmax);
  size_t vbase = (size_t)bc * 64 * 64;
  #pragma unroll
  for (int p = 0; p < 16; ++p) vs[tid + p * 256] = V[vbase + tid + p * 256];
  __syncthreads();

  size_t kbase = (size_t)bc * 64 * 256;
  float acc[64];
  #pragma unroll
  for (int e = 0; e < 64; ++e) acc[e] = 0.f;
  float z = 0.f;

  for (int pos = 0; pos < 64; ++pos) {
    float kj = RATIO * (__expf(kd[kbase + (size_t)pos * 256 + tid] - m) + KEPS);
    z += kj;
    #pragma unroll
    for (int e4 = 0; e4 < 16; ++e4) {
      float4 vv = *(const float4*)&vs[pos * 64 + e4 * 4];
      acc[e4 * 4 + 0] += kj * vv.x;
      acc[e4 * 4 + 1] += kj * vv.y;
      acc[e4 * 4 + 2] += kj * vv.z;
      acc[e4 * 4 + 3] += kj * vv.w;
    }
  }
  size_t sb = (size_t)bc * 16384 + (size_t)tid * 64;
  #pragma unroll
  for (int e4 = 0; e4 < 16; ++e4) {
    float4 o = {acc[e4 * 4], acc[e4 * 4 + 1], acc[e4 * 4 + 2], acc[e4 * 4 + 3]};
    *(float4*)&S[sb + e4 * 4] = o;
  }
  Z[(size_t)bc * 256 + tid] = z;
}

// ---------------------------------------------------------------------------
// K3: exclusive prefix over the 64 chunks per (bh), in place.
// blocks 0..1023: S elements; blocks 1024..1039: Z elements.
__global__ __launch_bounds__(256) void prefix_kernel(float* __restrict__ S,
                                                     float* __restrict__ Z)
{
  int b = blockIdx.x;
  if (b < 1024) {
    int flat = b * 256 + threadIdx.x;     // 262144 = 16 bh * 16384
    int bh = flat >> 14;
    int idx = flat & 16383;
    size_t base = (size_t)bh * 64 * 16384 + idx;
    float run = 0.f;
    for (int c = 0; c < 64; ++c) {
      size_t a = base + (size_t)c * 16384;
      float t = S[a]; S[a] = run; run += t;
    }
  } else {
    int bh = b - 1024;
    int j = threadIdx.x;
    size_t base = (size_t)bh * 16384 + j;   // Z: [bh*64+c]*256 + j
    float run = 0.f;
    for (int c = 0; c < 64; ++c) {
      size_t a = base + (size_t)c * 256;
      float t = Z[a]; Z[a] = run; run += t;
    }
  }
}

// ---------------------------------------------------------------------------
// K4a: masked intra-chunk scores A[i][t] = qp_i . kp_t (t<=i) and
// Dinv[i] = 1/( sum_j qp[i][j]*(z_ex[j]+eps) + rowsum(masked A) ).
// block = (bh,c); thread (i = tid&63, tb = tid>>6) owns A[i][tb*16..+16).
__global__ __launch_bounds__(256) void score_kernel(
    const float* __restrict__ qp, const float* __restrict__ kd,
    const unsigned int* __restrict__ kmax, const float* __restrict__ Z,
    float* __restrict__ A, float* __restrict__ Dinv)
{
  __shared__ float qt[64 * 65];   // [jj][i]
  __shared__ float kt[64 * 68];   // [jj][t], pad 68 for aligned b128 reads
  __shared__ float red[256];

  int bc = blockIdx.x, tid = threadIdx.x;
  int i = tid & 63, tb = tid >> 6;
  float m = fdec(*kmax);
  size_t base = (size_t)bc * 64 * 256;
  const float* zp = Z + (size_t)bc * 256;

  float acc[16];
  #pragma unroll
  for (int t2 = 0; t2 < 16; ++t2) acc[t2] = 0.f;
  float dacc = 0.f;

  for (int jt = 0; jt < 4; ++jt) {
    __syncthreads();
    #pragma unroll
    for (int p = 0; p < 16; ++p) {
      int idx = tid + p * 256;
      int il = idx >> 6, jj = idx & 63;
      size_t g = base + (size_t)il * 256 + jt * 64 + jj;
      qt[jj * 65 + il] = qp[g];
      kt[jj * 68 + il] = RATIO * (__expf(kd[g] - m) + KEPS);
    }
    __syncthreads();
    for (int jj = 0; jj < 64; ++jj) {
      float qv = qt[jj * 65 + i];
      float4 k0 = *(const float4*)&kt[jj * 68 + tb * 16 + 0];
      float4 k1 = *(const float4*)&kt[jj * 68 + tb * 16 + 4];
      float4 k2 = *(const float4*)&kt[jj * 68 + tb * 16 + 8];
      float4 k3 = *(const float4*)&kt[jj * 68 + tb * 16 + 12];
      acc[0]  += qv * k0.x; acc[1]  += qv * k0.y; acc[2]  += qv * k0.z; acc[3]  += qv * k0.w;
      acc[4]  += qv * k1.x; acc[5]  += qv * k1.y; acc[6]  += qv * k1.z; acc[7]  += qv * k1.w;
      acc[8]  += qv * k2.x; acc[9]  += qv * k2.y; acc[10] += qv * k2.z; acc[11] += qv * k2.w;
      acc[12] += qv * k3.x; acc[13] += qv * k3.y; acc[14] += qv * k3.z; acc[15] += qv * k3.w;
      dacc += qv * (zp[jt * 64 + jj] + AEPS);
    }
  }

  float msum = 0.f;
  float av[16];
  #pragma unroll
  for (int tt = 0; tt < 16; ++tt) {
    int t = tb * 16 + tt;
    float val = (t <= i) ? acc[tt] : 0.f;
    av[tt] = val; msum += val;
  }
  size_t ab = (size_t)bc * 4096 + (size_t)i * 64 + tb * 16;
  #pragma unroll
  for (int t4 = 0; t4 < 4; ++t4) {
    float4 o = {av[t4 * 4], av[t4 * 4 + 1], av[t4 * 4 + 2], av[t4 * 4 + 3]};
    *(float4*)&A[ab + t4 * 4] = o;
  }
  red[tb * 64 + i] = msum;
  __syncthreads();
  if (tb == 0) {
    float rs = red[i] + red[64 + i] + red[128 + i] + red[192 + i];
    Dinv[(size_t)bc * 64 + i] = 1.f / (dacc + rs);
  }
}

// ---------------------------------------------------------------------------
// K4b: out[i][e] = Dinv[i] * ( sum_j qp[i][j]*Sprefix[j][e] + sum_t A[i][t]*v[t][e] )
// block = (bh,c); thread (i = tid&63, eg = tid>>6) owns 16 e-columns of row i.
__global__ __launch_bounds__(256) void out_kernel(
    const float* __restrict__ qp, const float* __restrict__ S,
    const float* __restrict__ A, const float* __restrict__ Dinv,
    const float* __restrict__ V, float* __restrict__ out)
{
  __shared__ float As[64 * 65];   // [i][t]
  __shared__ float vs[4096];      // [t][e]
  __shared__ float qt[32 * 65];   // [jj][i] for a 32-wide j tile
  __shared__ float Sp[2048];      // [jj][e] Sprefix tile

  int bc = blockIdx.x, tid = threadIdx.x;
  int i = tid & 63, eg = tid >> 6;

  size_t vbase = (size_t)bc * 64 * 64;
  #pragma unroll
  for (int p = 0; p < 16; ++p) {
    int idx = tid + p * 256;
    int il = idx >> 6, t = idx & 63;
    As[il * 65 + t] = A[(size_t)bc * 4096 + idx];
    vs[idx] = V[vbase + idx];
  }

  float acc[16];
  #pragma unroll
  for (int t2 = 0; t2 < 16; ++t2) acc[t2] = 0.f;

  size_t qbase = (size_t)bc * 64 * 256;
  size_t sbase = (size_t)bc * 16384;

  for (int jt = 0; jt < 8; ++jt) {
    __syncthreads();
    #pragma unroll
    for (int p = 0; p < 8; ++p) {
      int idx = tid + p * 256;         // 2048
      int il = idx >> 5, jj = idx & 31;
      qt[jj * 65 + il] = qp[qbase + (size_t)il * 256 + jt * 32 + jj];
      Sp[idx] = S[sbase + (size_t)jt * 2048 + idx];
    }
    __syncthreads();
    for (int jj = 0; jj < 32; ++jj) {
      float qv = qt[jj * 65 + i];
      float4 s0 = *(const float4*)&Sp[jj * 64 + eg * 16 + 0];
      float4 s1 = *(const float4*)&Sp[jj * 64 + eg * 16 + 4];
      float4 s2 = *(const float4*)&Sp[jj * 64 + eg * 16 + 8];
      float4 s3 = *(const float4*)&Sp[jj * 64 + eg * 16 + 12];
      acc[0]  += qv * s0.x; acc[1]  += qv * s0.y; acc[2]  += qv * s0.z; acc[3]  += qv * s0.w;
      acc[4]  += qv * s1.x; acc[5]  += qv * s1.y; acc[6]  += qv * s1.z; acc[7]  += qv * s1.w;
      acc[8]  += qv * s2.x; acc[9]  += qv * s2.y; acc[10] += qv * s2.z; acc[11] += qv * s2.w;
      acc[12] += qv * s3.x; acc[13] += qv * s3.y; acc[14] += qv * s3.z; acc[15] += qv * s3.w;
    }
  }

  // intra-chunk part: A stored pre-masked (zeros above diagonal)
  for (int t = 0; t < 64; ++t) {
    float av = As[i * 65 + t];
    float4 v0 = *(const float4*)&vs[t * 64 + eg * 16 + 0];
    float4 v1 = *(const float4*)&vs[t * 64 + eg * 16 + 4];
    float4 v2 = *(const float4*)&vs[t * 64 + eg * 16 + 8];
    float4 v3 = *(const float4*)&vs[t * 64 + eg * 16 + 12];
    acc[0]  += av * v0.x; acc[1]  += av * v0.y; acc[2]  += av * v0.z; acc[3]  += av * v0.w;
    acc[4]  += av * v1.x; acc[5]  += av * v1.y; acc[6]  += av * v1.z; acc[7]  += av * v1.w;
    acc[8]  += av * v2.x; acc[9]  += av * v2.y; acc[10] += av * v2.z; acc[11] += av * v2.w;
    acc[12] += av * v3.x; acc[13] += av * v3.y; acc[14] += av * v3.z; acc[15] += av * v3.w;
  }

  float dinv = Dinv[(size_t)bc * 64 + i];
  size_t ob = (size_t)bc * 4096 + (size_t)i * 64 + eg * 16;
  #pragma unroll
  for (int e4 = 0; e4 < 4; ++e4) {
    float4 o = {acc[e4 * 4] * dinv, acc[e4 * 4 + 1] * dinv,
                acc[e4 * 4 + 2] * dinv, acc[e4 * 4 + 3] * dinv};
    *(float4*)&out[ob + e4 * 4] = o;
  }
}

// ---------------------------------------------------------------------------
extern "C" void kernel_launch(void* const* d_in, const int* in_sizes, int n_in,
                              void* d_out, int out_size, void* d_ws, size_t ws_size,
                              hipStream_t stream)
{
  const float* q = (const float*)d_in[0];
  const float* k = (const float*)d_in[1];
  const float* v = (const float*)d_in[2];
  const float* P = (const float*)d_in[3];
  float* out = (float*)d_out;
  float* ws = (float*)d_ws;

  float* qp = ws + QP_OFF;
  float* kd = ws + KD_OFF;
  float* S  = ws + S_OFF;
  float* Z  = ws + Z_OFF;
  float* A  = ws + A_OFF;
  float* Dinv = ws + DINV_OFF;
  unsigned int* kmax = (unsigned int*)(ws + KMAX_OFF);

  hipMemsetAsync(kmax, 0, 4, stream);   // enc(x) > 0 for all finite x
  feat_kernel<<<2048, 256, 0, stream>>>(q, k, P, qp, kd, kmax);
  chunksum_kernel<<<1024, 256, 0, stream>>>(kd, v, kmax, S, Z);
  prefix_kernel<<<1040, 256, 0, stream>>>(S, Z);
  score_kernel<<<1024, 256, 0, stream>>>(qp, kd, kmax, Z, A, Dinv);
  out_kernel<<<1024, 256, 0, stream>>>(qp, S, A, Dinv, v, out);
}

// Round 2
// 308.132 us; speedup vs baseline: 1.1105x; 1.1105x over previous
//
#include <hip/hip_runtime.h>

// Performer causal linear attention, MI355X. Round 2: bf16 intermediates +
// fused score/out kernel (A matrix never leaves LDS).
// b=2 h=8 n=4096 d=64 r=256 e=64, chunk=64.
//
// Pipeline:
//  K1 feat:     q,k -> qp (bf16), E = exp(dash - diag) unscaled (bf16), kmax
//  K2 chunksum: E,V -> per-chunk S_c (bf16, layout [bc][e][j]), Z (fp32)
//  K3 prefix:   exclusive prefix over chunks (fp32 accum, bf16 storage)
//  K4 fused:    scores A (LDS only) + Dinv + output

typedef unsigned short ushort_t;

#define KEPS 1e-4f
#define AEPS 1e-6f
#define NORMIZER 0.35355339059327373f   // 64^-0.25
#define RATIO 0.0625f                   // 256^-0.5

__device__ __forceinline__ unsigned fenc(float f) {
  unsigned u = __float_as_uint(f);
  return (u & 0x80000000u) ? ~u : (u | 0x80000000u);
}
__device__ __forceinline__ float fdec(unsigned e) {
  unsigned u = (e & 0x80000000u) ? (e ^ 0x80000000u) : ~e;
  return __uint_as_float(u);
}
__device__ __forceinline__ ushort_t bf16r(float f) {   // RNE
  unsigned u = __float_as_uint(f);
  return (ushort_t)((u + 0x7fffu + ((u >> 16) & 1u)) >> 16);
}
__device__ __forceinline__ float ubf(ushort_t h) {
  return __uint_as_float((unsigned)h << 16);
}

// ---------------------------------------------------------------------------
// K1: feature GEMM. blocks 0..1023 -> q, 1024..2047 -> k.
__global__ __launch_bounds__(256) void feat_kernel(
    const float* __restrict__ Q, const float* __restrict__ K,
    const float* __restrict__ P, ushort_t* __restrict__ qp,
    ushort_t* __restrict__ E, unsigned int* __restrict__ kmax)
{
  __shared__ float xs[64 * 68];
  __shared__ float ps[64 * 132];
  __shared__ float red[4];

  int bid = blockIdx.x;
  int tid = threadIdx.x;
  bool isK = bid >= 1024;
  const float* X = isK ? K : Q;
  int rowbase = (isK ? bid - 1024 : bid) * 64;

  #pragma unroll
  for (int p = 0; p < 16; ++p) {
    int idx = tid + p * 256;
    int rl = idx >> 6, kl = idx & 63;
    xs[kl * 68 + rl] = X[(size_t)(rowbase + rl) * 64 + kl];
  }

  int cg = tid & 31;
  int rg = tid >> 5;

  float dash[2][8][4];

  #pragma unroll
  for (int pass = 0; pass < 2; ++pass) {
    __syncthreads();
    #pragma unroll
    for (int p = 0; p < 32; ++p) {
      int idx = tid + p * 256;
      int col = idx >> 6, kl = idx & 63;
      ps[kl * 132 + col] = P[(size_t)(pass * 128 + col) * 64 + kl];
    }
    __syncthreads();

    float acc[32];
    #pragma unroll
    for (int t2 = 0; t2 < 32; ++t2) acc[t2] = 0.f;

    for (int kl = 0; kl < 64; ++kl) {
      float4 pv  = *(const float4*)&ps[kl * 132 + cg * 4];
      float4 xv0 = *(const float4*)&xs[kl * 68 + rg * 8];
      float4 xv1 = *(const float4*)&xs[kl * 68 + rg * 8 + 4];
      float xr[8] = {xv0.x, xv0.y, xv0.z, xv0.w, xv1.x, xv1.y, xv1.z, xv1.w};
      #pragma unroll
      for (int rr = 0; rr < 8; ++rr) {
        acc[rr * 4 + 0] += xr[rr] * pv.x;
        acc[rr * 4 + 1] += xr[rr] * pv.y;
        acc[rr * 4 + 2] += xr[rr] * pv.z;
        acc[rr * 4 + 3] += xr[rr] * pv.w;
      }
    }
    #pragma unroll
    for (int rr = 0; rr < 8; ++rr)
      #pragma unroll
      for (int cc = 0; cc < 4; ++cc)
        dash[pass][rr][cc] = NORMIZER * acc[rr * 4 + cc];
  }

  float diag[8];
  #pragma unroll
  for (int rr = 0; rr < 8; ++rr) {
    int row = rg * 8 + rr;
    float a = xs[cg * 68 + row];
    float b = xs[(cg + 32) * 68 + row];
    float p = a * a + b * b;
    #pragma unroll
    for (int m = 1; m < 32; m <<= 1) p += __shfl_xor(p, m, 64);
    diag[rr] = 0.0625f * p;
  }

  if (!isK) {
    #pragma unroll
    for (int rr = 0; rr < 8; ++rr) {
      float mx = -3.0e38f;
      #pragma unroll
      for (int pass = 0; pass < 2; ++pass)
        #pragma unroll
        for (int cc = 0; cc < 4; ++cc)
          mx = fmaxf(mx, dash[pass][rr][cc]);
      #pragma unroll
      for (int m = 1; m < 32; m <<= 1) mx = fmaxf(mx, __shfl_xor(mx, m, 64));
      int row = rowbase + rg * 8 + rr;
      #pragma unroll
      for (int pass = 0; pass < 2; ++pass) {
        ushort4 o;
        o.x = bf16r(RATIO * (__expf(dash[pass][rr][0] - diag[rr] - mx) + KEPS));
        o.y = bf16r(RATIO * (__expf(dash[pass][rr][1] - diag[rr] - mx) + KEPS));
        o.z = bf16r(RATIO * (__expf(dash[pass][rr][2] - diag[rr] - mx) + KEPS));
        o.w = bf16r(RATIO * (__expf(dash[pass][rr][3] - diag[rr] - mx) + KEPS));
        *(ushort4*)&qp[(size_t)row * 256 + pass * 128 + cg * 4] = o;
      }
    }
  } else {
    float bmax = -3.0e38f;
    #pragma unroll
    for (int rr = 0; rr < 8; ++rr) {
      int row = rowbase + rg * 8 + rr;
      #pragma unroll
      for (int pass = 0; pass < 2; ++pass) {
        ushort4 o;
        o.x = bf16r(__expf(dash[pass][rr][0] - diag[rr]));
        o.y = bf16r(__expf(dash[pass][rr][1] - diag[rr]));
        o.z = bf16r(__expf(dash[pass][rr][2] - diag[rr]));
        o.w = bf16r(__expf(dash[pass][rr][3] - diag[rr]));
        bmax = fmaxf(bmax, fmaxf(fmaxf(dash[pass][rr][0], dash[pass][rr][1]),
                                 fmaxf(dash[pass][rr][2], dash[pass][rr][3])));
        *(ushort4*)&E[(size_t)row * 256 + pass * 128 + cg * 4] = o;
      }
    }
    #pragma unroll
    for (int m = 1; m < 64; m <<= 1) bmax = fmaxf(bmax, __shfl_xor(bmax, m, 64));
    if ((tid & 63) == 0) red[tid >> 6] = bmax;
    __syncthreads();
    if (tid == 0) {
      float m4 = fmaxf(fmaxf(red[0], red[1]), fmaxf(red[2], red[3]));
      atomicMax(kmax, fenc(m4));
    }
  }
}

// ---------------------------------------------------------------------------
// K2: per-chunk sums. kp = c1*E + c0. S layout [bc][e][j] (coalesced writes).
__global__ __launch_bounds__(256) void chunksum_kernel(
    const ushort_t* __restrict__ E, const float* __restrict__ V,
    const unsigned int* __restrict__ kmax,
    ushort_t* __restrict__ S, float* __restrict__ Z)
{
  __shared__ float vs[4096];
  int bc = blockIdx.x, tid = threadIdx.x;
  float m = fdec(*kmax);
  float c1 = RATIO * __expf(-m);
  const float c0 = RATIO * KEPS;
  size_t vbase = (size_t)bc * 4096;
  #pragma unroll
  for (int p = 0; p < 16; ++p) vs[tid + p * 256] = V[vbase + tid + p * 256];
  __syncthreads();

  size_t kbase = (size_t)bc * 16384;
  float acc[64];
  #pragma unroll
  for (int e = 0; e < 64; ++e) acc[e] = 0.f;
  float z = 0.f;

  for (int pos = 0; pos < 64; ++pos) {
    float kj = c1 * ubf(E[kbase + (size_t)pos * 256 + tid]) + c0;
    z += kj;
    #pragma unroll
    for (int e4 = 0; e4 < 16; ++e4) {
      float4 vv = *(const float4*)&vs[pos * 64 + e4 * 4];
      acc[e4 * 4 + 0] += kj * vv.x;
      acc[e4 * 4 + 1] += kj * vv.y;
      acc[e4 * 4 + 2] += kj * vv.z;
      acc[e4 * 4 + 3] += kj * vv.w;
    }
  }
  #pragma unroll
  for (int e = 0; e < 64; ++e)
    S[kbase + (size_t)e * 256 + tid] = bf16r(acc[e]);
  Z[(size_t)bc * 256 + tid] = z;
}

// ---------------------------------------------------------------------------
// K3: exclusive prefix over 64 chunks per bh, in place. fp32 running sum.
__global__ __launch_bounds__(256) void prefix_kernel(ushort_t* __restrict__ S,
                                                     float* __restrict__ Z)
{
  int b = blockIdx.x;
  if (b < 1024) {
    int flat = b * 256 + threadIdx.x;
    int bh = flat >> 14;
    int idx = flat & 16383;
    size_t base = (size_t)bh * 1048576 + idx;
    float run = 0.f;
    for (int c = 0; c < 64; ++c) {
      size_t a = base + (size_t)c * 16384;
      float t = ubf(S[a]); S[a] = bf16r(run); run += t;
    }
  } else {
    int bh = b - 1024;
    int j = threadIdx.x;
    size_t base = (size_t)bh * 16384 + j;
    float run = 0.f;
    for (int c = 0; c < 64; ++c) {
      size_t a = base + (size_t)c * 256;
      float t = Z[a]; Z[a] = run; run += t;
    }
  }
}

// ---------------------------------------------------------------------------
// K4: fused scores + denominator + output. block = (bh,c).
// Phase 1: A[i][t] = qp_i . kp_t (masked) -> LDS; Dinv -> LDS.
// Phase 2: out[i][e] = Dinv[i] * (qp_i . Sprefix[:,e] + sum_t A[i][t] v[t][e])
__global__ __launch_bounds__(256) void fused_kernel(
    const ushort_t* __restrict__ qp, const ushort_t* __restrict__ E,
    const unsigned int* __restrict__ kmax, const float* __restrict__ Z,
    const ushort_t* __restrict__ S, const float* __restrict__ V,
    float* __restrict__ out)
{
  __shared__ float smem[12992];
  float* As    = smem;            // [64][65] scalar r/w, conflict-free
  float* dinvs = smem + 4160;     // [64]
  float* red   = smem + 4224;     // [256]
  float* scr   = smem + 4480;     // 8512 floats, phase-aliased

  int bc = blockIdx.x, tid = threadIdx.x;
  int i = tid & 63, tb = tid >> 6;       // tb is wave-uniform
  float m = fdec(*kmax);
  float c1 = RATIO * __expf(-m);
  const float c0 = RATIO * KEPS;
  size_t base = (size_t)bc * 16384;
  const float* zp = Z + (size_t)bc * 256;

  // ---- phase 1: scores ----
  float* qt = scr;                // [64][65] scalar-read
  float* kt = scr + 4160;        // [64][68] float4-read (16B-aligned rows)

  float acc[16];
  #pragma unroll
  for (int t2 = 0; t2 < 16; ++t2) acc[t2] = 0.f;
  float dacc = 0.f;

  for (int jt = 0; jt < 4; ++jt) {
    __syncthreads();
    #pragma unroll
    for (int p = 0; p < 16; ++p) {
      int idx = tid + p * 256;
      int il = idx >> 6, jj = idx & 63;
      size_t g = base + (size_t)il * 256 + jt * 64 + jj;
      qt[jj * 65 + il] = ubf(qp[g]);
      kt[jj * 68 + il] = c1 * ubf(E[g]) + c0;
    }
    __syncthreads();
    for (int jj = 0; jj < 64; ++jj) {
      float qv = qt[jj * 65 + i];
      float4 k0 = *(const float4*)&kt[jj * 68 + tb * 16 + 0];
      float4 k1 = *(const float4*)&kt[jj * 68 + tb * 16 + 4];
      float4 k2 = *(const float4*)&kt[jj * 68 + tb * 16 + 8];
      float4 k3 = *(const float4*)&kt[jj * 68 + tb * 16 + 12];
      acc[0]  += qv * k0.x; acc[1]  += qv * k0.y; acc[2]  += qv * k0.z; acc[3]  += qv * k0.w;
      acc[4]  += qv * k1.x; acc[5]  += qv * k1.y; acc[6]  += qv * k1.z; acc[7]  += qv * k1.w;
      acc[8]  += qv * k2.x; acc[9]  += qv * k2.y; acc[10] += qv * k2.z; acc[11] += qv * k2.w;
      acc[12] += qv * k3.x; acc[13] += qv * k3.y; acc[14] += qv * k3.z; acc[15] += qv * k3.w;
      dacc += qv * (zp[jt * 64 + jj] + AEPS);
    }
  }

  // mask + store A to LDS, row-sum for denominator
  float msum = 0.f;
  #pragma unroll
  for (int tt = 0; tt < 16; ++tt) {
    int t = tb * 16 + tt;
    float val = (t <= i) ? acc[tt] : 0.f;
    As[i * 65 + t] = val;
    msum += val;
  }
  red[tb * 64 + i] = msum;
  __syncthreads();
  if (tb == 0) {
    float rs = red[i] + red[64 + i] + red[128 + i] + red[192 + i];
    dinvs[i] = 1.f / (dacc + rs);
  }
  __syncthreads();

  // ---- phase 2: output ----
  float* vs  = scr;               // [64][64], broadcast float4 reads
  float* qt2 = scr + 4096;        // [32][65] scalar-read
  float* Sp  = scr + 6176;        // [32][68] float4-read
  int eg = tb;

  #pragma unroll
  for (int p = 0; p < 16; ++p)
    vs[tid + p * 256] = V[(size_t)bc * 4096 + tid + p * 256];

  float oacc[16];
  #pragma unroll
  for (int t2 = 0; t2 < 16; ++t2) oacc[t2] = 0.f;

  for (int jt = 0; jt < 8; ++jt) {
    __syncthreads();
    #pragma unroll
    for (int p = 0; p < 8; ++p) {
      int idx = tid + p * 256;
      int hi = idx >> 5, jj = idx & 31;
      qt2[jj * 65 + hi] = ubf(qp[base + (size_t)hi * 256 + jt * 32 + jj]);
      Sp[jj * 68 + hi]  = ubf(S[base + (size_t)hi * 256 + jt * 32 + jj]);
    }
    __syncthreads();
    for (int jj = 0; jj < 32; ++jj) {
      float qv = qt2[jj * 65 + i];
      float4 s0 = *(const float4*)&Sp[jj * 68 + eg * 16 + 0];
      float4 s1 = *(const float4*)&Sp[jj * 68 + eg * 16 + 4];
      float4 s2 = *(const float4*)&Sp[jj * 68 + eg * 16 + 8];
      float4 s3 = *(const float4*)&Sp[jj * 68 + eg * 16 + 12];
      oacc[0]  += qv * s0.x; oacc[1]  += qv * s0.y; oacc[2]  += qv * s0.z; oacc[3]  += qv * s0.w;
      oacc[4]  += qv * s1.x; oacc[5]  += qv * s1.y; oacc[6]  += qv * s1.z; oacc[7]  += qv * s1.w;
      oacc[8]  += qv * s2.x; oacc[9]  += qv * s2.y; oacc[10] += qv * s2.z; oacc[11] += qv * s2.w;
      oacc[12] += qv * s3.x; oacc[13] += qv * s3.y; oacc[14] += qv * s3.z; oacc[15] += qv * s3.w;
    }
  }

  for (int t = 0; t < 64; ++t) {
    float av = As[i * 65 + t];
    float4 v0 = *(const float4*)&vs[t * 64 + eg * 16 + 0];
    float4 v1 = *(const float4*)&vs[t * 64 + eg * 16 + 4];
    float4 v2 = *(const float4*)&vs[t * 64 + eg * 16 + 8];
    float4 v3 = *(const float4*)&vs[t * 64 + eg * 16 + 12];
    oacc[0]  += av * v0.x; oacc[1]  += av * v0.y; oacc[2]  += av * v0.z; oacc[3]  += av * v0.w;
    oacc[4]  += av * v1.x; oacc[5]  += av * v1.y; oacc[6]  += av * v1.z; oacc[7]  += av * v1.w;
    oacc[8]  += av * v2.x; oacc[9]  += av * v2.y; oacc[10] += av * v2.z; oacc[11] += av * v2.w;
    oacc[12] += av * v3.x; oacc[13] += av * v3.y; oacc[14] += av * v3.z; oacc[15] += av * v3.w;
  }

  float dv = dinvs[i];
  size_t ob = (size_t)bc * 4096 + (size_t)i * 64 + eg * 16;
  #pragma unroll
  for (int e4 = 0; e4 < 4; ++e4) {
    float4 o = {oacc[e4 * 4] * dv, oacc[e4 * 4 + 1] * dv,
                oacc[e4 * 4 + 2] * dv, oacc[e4 * 4 + 3] * dv};
    *(float4*)&out[ob + e4 * 4] = o;
  }
}

// ---------------------------------------------------------------------------
extern "C" void kernel_launch(void* const* d_in, const int* in_sizes, int n_in,
                              void* d_out, int out_size, void* d_ws, size_t ws_size,
                              hipStream_t stream)
{
  const float* q = (const float*)d_in[0];
  const float* k = (const float*)d_in[1];
  const float* v = (const float*)d_in[2];
  const float* P = (const float*)d_in[3];
  float* out = (float*)d_out;

  ushort_t* qp = (ushort_t*)d_ws;
  ushort_t* E  = qp + 16777216;
  ushort_t* S  = E + 16777216;
  float*    Z  = (float*)(S + 16777216);
  unsigned int* kmax = (unsigned int*)(Z + 262144);

  hipMemsetAsync(kmax, 0, 4, stream);
  feat_kernel<<<2048, 256, 0, stream>>>(q, k, P, qp, E, kmax);
  chunksum_kernel<<<1024, 256, 0, stream>>>(E, v, kmax, S, Z);
  prefix_kernel<<<1040, 256, 0, stream>>>(S, Z);
  fused_kernel<<<1024, 256, 0, stream>>>(qp, E, kmax, Z, S, v, out);
}

// Round 3
// 278.673 us; speedup vs baseline: 1.2279x; 1.1057x over previous
//
#include <hip/hip_runtime.h>

// Performer causal linear attention, MI355X. Round 3: MFMA everywhere GEMM-shaped.
// b=2 h=8 n=4096 d=64 r=256 e=64, chunk=64.
//
//  K0 pconv:    P fp32 -> Phi/Plo bf16 (split precision)
//  K1 feat:     dash = (Xhi+Xlo)*(Phi+Plo) via 3 MFMAs; qp/E bf16 + kmax
//  K2 chunksum: E,V -> per-chunk S_c (bf16 [bc][e][j]), Z (fp32)   [VALU]
//  K3 prefix:   exclusive prefix over chunks                        [VALU]
//  K4 fused:    MFMA scores (B-frags straight from global E) + Dinv +
//               MFMA output ([Qp|A_sc]·[Sp;Vt]); A never leaves LDS.

typedef unsigned short ushort_t;
typedef __attribute__((ext_vector_type(8))) short bf16x8;
typedef __attribute__((ext_vector_type(4))) float f32x4;

#define KEPS 1e-4f
#define AEPS 1e-6f
#define NORMIZER 0.35355339059327373f   // 64^-0.25
#define RATIO 0.0625f                   // 256^-0.5

__device__ __forceinline__ unsigned fenc(float f) {
  unsigned u = __float_as_uint(f);
  return (u & 0x80000000u) ? ~u : (u | 0x80000000u);
}
__device__ __forceinline__ float fdec(unsigned e) {
  unsigned u = (e & 0x80000000u) ? (e ^ 0x80000000u) : ~e;
  return __uint_as_float(u);
}
__device__ __forceinline__ ushort_t bf16r(float f) {   // RNE
  unsigned u = __float_as_uint(f);
  return (ushort_t)((u + 0x7fffu + ((u >> 16) & 1u)) >> 16);
}
__device__ __forceinline__ float ubf(ushort_t h) {
  return __uint_as_float((unsigned)h << 16);
}

// ---------------------------------------------------------------------------
// K0: split P into bf16 hi/lo.
__global__ __launch_bounds__(256) void pconv_kernel(
    const float* __restrict__ P, ushort_t* __restrict__ Phi,
    ushort_t* __restrict__ Plo)
{
  int idx = blockIdx.x * 1024 + threadIdx.x;
  #pragma unroll
  for (int p = 0; p < 4; ++p) {
    int i = idx + p * 256;
    float x = P[i];
    ushort_t h = bf16r(x);
    Phi[i] = h;
    Plo[i] = bf16r(x - ubf(h));
  }
}

// ---------------------------------------------------------------------------
// K1: feature map via MFMA. blocks 0..1023 -> q, 1024..2047 -> k.
// Per block: 64 rows x 256 cols. dash = NORMIZER*(X*P^T), split-precision.
__global__ __launch_bounds__(256) void feat_mfma(
    const float* __restrict__ Q, const float* __restrict__ K,
    const ushort_t* __restrict__ Phi, const ushort_t* __restrict__ Plo,
    ushort_t* __restrict__ qp, ushort_t* __restrict__ E,
    unsigned int* __restrict__ kmax)
{
  __shared__ ushort_t Xhi[64 * 72];   // pitch 72 (144B, 16B-aligned rows)
  __shared__ ushort_t Xlo[64 * 72];
  __shared__ float diagS[64];
  __shared__ float red[256];
  __shared__ float redm[4];

  int bid = blockIdx.x, tid = threadIdx.x;
  bool isK = bid >= 1024;
  const float* X = isK ? K : Q;
  size_t rowbase = (size_t)(isK ? bid - 1024 : bid) * 64;

  // stage X -> hi/lo bf16 (coalesced float4 reads)
  #pragma unroll
  for (int p = 0; p < 4; ++p) {
    int idx = tid + p * 256;          // 1024 float4 groups
    int row = idx >> 4, c4 = idx & 15;
    float4 x = *(const float4*)&X[(rowbase + row) * 64 + c4 * 4];
    ushort4 h, l;
    h.x = bf16r(x.x); l.x = bf16r(x.x - ubf(h.x));
    h.y = bf16r(x.y); l.y = bf16r(x.y - ubf(h.y));
    h.z = bf16r(x.z); l.z = bf16r(x.z - ubf(h.z));
    h.w = bf16r(x.w); l.w = bf16r(x.w - ubf(h.w));
    *(ushort4*)&Xhi[row * 72 + c4 * 4] = h;
    *(ushort4*)&Xlo[row * 72 + c4 * 4] = l;
  }
  __syncthreads();

  // per-row diag = sumsq/16
  {
    int row = tid & 63, seg = tid >> 6;
    float s = 0.f;
    #pragma unroll
    for (int i2 = 0; i2 < 16; ++i2) {
      int o = row * 72 + seg * 16 + i2;
      float v = ubf(Xhi[o]) + ubf(Xlo[o]);
      s += v * v;
    }
    red[seg * 64 + row] = s;
  }
  __syncthreads();
  if (tid < 64)
    diagS[tid] = 0.0625f * (red[tid] + red[64 + tid] + red[128 + tid] + red[192 + tid]);
  __syncthreads();

  int lane = tid & 63, wv = tid >> 6;
  int n15 = lane & 15, quad = lane >> 4;

  // A-fragments (hi/lo), 2 k-steps of 32
  bf16x8 ah[2], al[2];
  #pragma unroll
  for (int ks = 0; ks < 2; ++ks) {
    int off = (16 * wv + n15) * 72 + quad * 8 + 32 * ks;
    ah[ks] = *(const bf16x8*)&Xhi[off];
    al[ks] = *(const bf16x8*)&Xlo[off];
  }

  f32x4 acc[16];
  #pragma unroll
  for (int tc = 0; tc < 16; ++tc) {
    f32x4 a = {0.f, 0.f, 0.f, 0.f};
    #pragma unroll
    for (int ks = 0; ks < 2; ++ks) {
      int poff = (16 * tc + n15) * 64 + quad * 8 + 32 * ks;
      bf16x8 bh = *(const bf16x8*)&Phi[poff];
      bf16x8 bl = *(const bf16x8*)&Plo[poff];
      a = __builtin_amdgcn_mfma_f32_16x16x32_bf16(ah[ks], bh, a, 0, 0, 0);
      a = __builtin_amdgcn_mfma_f32_16x16x32_bf16(ah[ks], bl, a, 0, 0, 0);
      a = __builtin_amdgcn_mfma_f32_16x16x32_bf16(al[ks], bh, a, 0, 0, 0);
    }
    acc[tc] = a;
  }

  // C/D layout: row = 16*wv + quad*4 + r, col = 16*tc + n15
  float dg[4];
  #pragma unroll
  for (int r = 0; r < 4; ++r) dg[r] = diagS[16 * wv + quad * 4 + r];

  if (!isK) {
    float mx[4] = {-3.0e38f, -3.0e38f, -3.0e38f, -3.0e38f};
    #pragma unroll
    for (int tc = 0; tc < 16; ++tc)
      #pragma unroll
      for (int r = 0; r < 4; ++r) mx[r] = fmaxf(mx[r], acc[tc][r]);
    #pragma unroll
    for (int r = 0; r < 4; ++r) {
      #pragma unroll
      for (int s = 1; s < 16; s <<= 1) mx[r] = fmaxf(mx[r], __shfl_xor(mx[r], s, 64));
    }
    #pragma unroll
    for (int r = 0; r < 4; ++r) {
      size_t row = rowbase + 16 * wv + quad * 4 + r;
      float sub = dg[r] + NORMIZER * mx[r];
      #pragma unroll
      for (int tc = 0; tc < 16; ++tc) {
        float val = RATIO * (__expf(NORMIZER * acc[tc][r] - sub) + KEPS);
        qp[row * 256 + 16 * tc + n15] = bf16r(val);
      }
    }
  } else {
    float bm = -3.0e38f;
    #pragma unroll
    for (int r = 0; r < 4; ++r) {
      size_t row = rowbase + 16 * wv + quad * 4 + r;
      #pragma unroll
      for (int tc = 0; tc < 16; ++tc) {
        float d = acc[tc][r];
        bm = fmaxf(bm, d);
        E[row * 256 + 16 * tc + n15] = bf16r(__expf(NORMIZER * d - dg[r]));
      }
    }
    #pragma unroll
    for (int s = 1; s < 64; s <<= 1) bm = fmaxf(bm, __shfl_xor(bm, s, 64));
    if (lane == 0) redm[wv] = bm;
    __syncthreads();
    if (tid == 0) {
      float m4 = fmaxf(fmaxf(redm[0], redm[1]), fmaxf(redm[2], redm[3]));
      atomicMax(kmax, fenc(NORMIZER * m4));
    }
  }
}

// ---------------------------------------------------------------------------
// K2: per-chunk sums. kp = c1*E + c0. S layout [bc][e][j].
__global__ __launch_bounds__(256) void chunksum_kernel(
    const ushort_t* __restrict__ E, const float* __restrict__ V,
    const unsigned int* __restrict__ kmax,
    ushort_t* __restrict__ S, float* __restrict__ Z)
{
  __shared__ float vs[4096];
  int bc = blockIdx.x, tid = threadIdx.x;
  float m = fdec(*kmax);
  float c1 = RATIO * __expf(-m);
  const float c0 = RATIO * KEPS;
  size_t vbase = (size_t)bc * 4096;
  #pragma unroll
  for (int p = 0; p < 16; ++p) vs[tid + p * 256] = V[vbase + tid + p * 256];
  __syncthreads();

  size_t kbase = (size_t)bc * 16384;
  float acc[64];
  #pragma unroll
  for (int e = 0; e < 64; ++e) acc[e] = 0.f;
  float z = 0.f;

  for (int pos = 0; pos < 64; ++pos) {
    float kj = c1 * ubf(E[kbase + (size_t)pos * 256 + tid]) + c0;
    z += kj;
    #pragma unroll
    for (int e4 = 0; e4 < 16; ++e4) {
      float4 vv = *(const float4*)&vs[pos * 64 + e4 * 4];
      acc[e4 * 4 + 0] += kj * vv.x;
      acc[e4 * 4 + 1] += kj * vv.y;
      acc[e4 * 4 + 2] += kj * vv.z;
      acc[e4 * 4 + 3] += kj * vv.w;
    }
  }
  #pragma unroll
  for (int e = 0; e < 64; ++e)
    S[kbase + (size_t)e * 256 + tid] = bf16r(acc[e]);
  Z[(size_t)bc * 256 + tid] = z;
}

// ---------------------------------------------------------------------------
// K3: exclusive prefix over 64 chunks per bh, in place.
__global__ __launch_bounds__(256) void prefix_kernel(ushort_t* __restrict__ S,
                                                     float* __restrict__ Z)
{
  int b = blockIdx.x;
  if (b < 1024) {
    int flat = b * 256 + threadIdx.x;
    int bh = flat >> 14;
    int idx = flat & 16383;
    size_t base = (size_t)bh * 1048576 + idx;
    float run = 0.f;
    for (int c = 0; c < 64; ++c) {
      size_t a = base + (size_t)c * 16384;
      float t = ubf(S[a]); S[a] = bf16r(run); run += t;
    }
  } else {
    int bh = b - 1024;
    int j = threadIdx.x;
    size_t base = (size_t)bh * 16384 + j;
    float run = 0.f;
    for (int c = 0; c < 64; ++c) {
      size_t a = base + (size_t)c * 256;
      float t = Z[a]; Z[a] = run; run += t;
    }
  }
}

// ---------------------------------------------------------------------------
// K4: fused MFMA scores + denominator + output. block = (bh,c).
__global__ __launch_bounds__(256) void fused_mfma(
    const ushort_t* __restrict__ qp, const ushort_t* __restrict__ E,
    const unsigned int* __restrict__ kmax, const float* __restrict__ Z,
    const ushort_t* __restrict__ S, const float* __restrict__ V,
    float* __restrict__ out)
{
  __shared__ ushort_t As[64 * 72];   // A_sc bf16, A-operand layout [i][t]
  __shared__ ushort_t Vt[64 * 72];   // V^T bf16 [e][t]
  __shared__ float zv[256];
  __shared__ float qsumS[64];
  __shared__ float dqS[64];

  int bc = blockIdx.x, tid = threadIdx.x;
  int lane = tid & 63, wv = tid >> 6;
  int n15 = lane & 15, quad = lane >> 4;
  float m = fdec(*kmax);
  float c1 = RATIO * __expf(-m);
  const float c0 = RATIO * KEPS;
  size_t base = (size_t)bc * 16384;

  // stage z (+eps) and V^T (cross-wave -> one barrier)
  zv[tid] = Z[(size_t)bc * 256 + tid] + AEPS;
  #pragma unroll
  for (int p = 0; p < 16; ++p) {
    int idx = tid + p * 256;
    int t = idx >> 6, e = idx & 63;
    Vt[e * 72 + t] = bf16r(V[(size_t)bc * 4096 + idx]);
  }
  __syncthreads();

  // Qp A-fragments: rows 16*wv + n15, 8 k-steps (held for both GEMMs)
  bf16x8 aQ[8];
  #pragma unroll
  for (int ks = 0; ks < 8; ++ks)
    aQ[ks] = *(const bf16x8*)&qp[base + (size_t)(16 * wv + n15) * 256 + quad * 8 + 32 * ks];

  // qsum + dq (= sum_j qp*(zex+eps)) for this lane's row; reduce over quads
  float qsum = 0.f, dq = 0.f;
  #pragma unroll
  for (int ks = 0; ks < 8; ++ks)
    #pragma unroll
    for (int j = 0; j < 8; ++j) {
      float qv = ubf((ushort_t)aQ[ks][j]);
      qsum += qv;
      dq += qv * zv[quad * 8 + 32 * ks + j];
    }
  qsum += __shfl_xor(qsum, 16, 64); qsum += __shfl_xor(qsum, 32, 64);
  dq   += __shfl_xor(dq, 16, 64);   dq   += __shfl_xor(dq, 32, 64);
  if (quad == 0) { qsumS[16 * wv + n15] = qsum; dqS[16 * wv + n15] = dq; }

  // ---- phase A: G = Qp * E^T, B-frags straight from global E ----
  float rs[4] = {0.f, 0.f, 0.f, 0.f};
  #pragma unroll
  for (int tc = 0; tc < 4; ++tc) {
    f32x4 g = {0.f, 0.f, 0.f, 0.f};
    #pragma unroll
    for (int ks = 0; ks < 8; ++ks) {
      bf16x8 b = *(const bf16x8*)&E[base + (size_t)(16 * tc + n15) * 256 + quad * 8 + 32 * ks];
      g = __builtin_amdgcn_mfma_f32_16x16x32_bf16(aQ[ks], b, g, 0, 0, 0);
    }
    #pragma unroll
    for (int r = 0; r < 4; ++r) {
      int i = 16 * wv + quad * 4 + r;
      int t = 16 * tc + n15;
      float val = (t <= i) ? (c1 * g[r] + c0 * qsumS[i]) : 0.f;
      As[i * 72 + t] = bf16r(val);
      rs[r] += val;
    }
  }

  float dinv[4];
  #pragma unroll
  for (int r = 0; r < 4; ++r) {
    float v = rs[r];
    #pragma unroll
    for (int s = 1; s < 16; s <<= 1) v += __shfl_xor(v, s, 64);
    int i = 16 * wv + quad * 4 + r;
    dinv[r] = 1.f / (dqS[i] + v);
  }

  // ---- phase C: out = [Qp | A_sc] * [Sp ; Vt] ----
  #pragma unroll
  for (int ec = 0; ec < 4; ++ec) {
    f32x4 o = {0.f, 0.f, 0.f, 0.f};
    #pragma unroll
    for (int ks = 0; ks < 8; ++ks) {
      bf16x8 b = *(const bf16x8*)&S[base + (size_t)(16 * ec + n15) * 256 + quad * 8 + 32 * ks];
      o = __builtin_amdgcn_mfma_f32_16x16x32_bf16(aQ[ks], b, o, 0, 0, 0);
    }
    #pragma unroll
    for (int ks = 0; ks < 2; ++ks) {
      bf16x8 a2 = *(const bf16x8*)&As[(16 * wv + n15) * 72 + quad * 8 + 32 * ks];
      bf16x8 b2 = *(const bf16x8*)&Vt[(16 * ec + n15) * 72 + quad * 8 + 32 * ks];
      o = __builtin_amdgcn_mfma_f32_16x16x32_bf16(a2, b2, o, 0, 0, 0);
    }
    #pragma unroll
    for (int r = 0; r < 4; ++r) {
      int i = 16 * wv + quad * 4 + r;
      out[(size_t)bc * 4096 + (size_t)i * 64 + 16 * ec + n15] = o[r] * dinv[r];
    }
  }
}

// ---------------------------------------------------------------------------
extern "C" void kernel_launch(void* const* d_in, const int* in_sizes, int n_in,
                              void* d_out, int out_size, void* d_ws, size_t ws_size,
                              hipStream_t stream)
{
  const float* q = (const float*)d_in[0];
  const float* k = (const float*)d_in[1];
  const float* v = (const float*)d_in[2];
  const float* P = (const float*)d_in[3];
  float* out = (float*)d_out;

  ushort_t* qp  = (ushort_t*)d_ws;
  ushort_t* E   = qp + 16777216;
  ushort_t* S   = E + 16777216;
  float*    Z   = (float*)(S + 16777216);
  ushort_t* Phi = (ushort_t*)(Z + 262144);
  ushort_t* Plo = Phi + 16384;
  unsigned int* kmax = (unsigned int*)(Plo + 16384);

  hipMemsetAsync(kmax, 0, 4, stream);
  pconv_kernel<<<16, 256, 0, stream>>>(P, Phi, Plo);
  feat_mfma<<<2048, 256, 0, stream>>>(q, k, Phi, Plo, qp, E, kmax);
  chunksum_kernel<<<1024, 256, 0, stream>>>(E, v, kmax, S, Z);
  prefix_kernel<<<1040, 256, 0, stream>>>(S, Z);
  fused_mfma<<<1024, 256, 0, stream>>>(qp, E, kmax, Z, S, v, out);
}

// Round 4
// 272.949 us; speedup vs baseline: 1.2536x; 1.0210x over previous
//
#include <hip/hip_runtime.h>

// Performer causal linear attention, MI355X. Round 4:
//  - feat: epilogue through LDS transpose -> coalesced 16B stores
//  - prefix: 8-deep batched prefetch (breaks the serialized scan chain)
// b=2 h=8 n=4096 d=64 r=256 e=64, chunk=64.

typedef unsigned short ushort_t;
typedef __attribute__((ext_vector_type(8))) short bf16x8;
typedef __attribute__((ext_vector_type(4))) float f32x4;

#define KEPS 1e-4f
#define AEPS 1e-6f
#define NORMIZER 0.35355339059327373f   // 64^-0.25
#define RATIO 0.0625f                   // 256^-0.5

__device__ __forceinline__ unsigned fenc(float f) {
  unsigned u = __float_as_uint(f);
  return (u & 0x80000000u) ? ~u : (u | 0x80000000u);
}
__device__ __forceinline__ float fdec(unsigned e) {
  unsigned u = (e & 0x80000000u) ? (e ^ 0x80000000u) : ~e;
  return __uint_as_float(u);
}
__device__ __forceinline__ ushort_t bf16r(float f) {   // RNE
  unsigned u = __float_as_uint(f);
  return (ushort_t)((u + 0x7fffu + ((u >> 16) & 1u)) >> 16);
}
__device__ __forceinline__ float ubf(ushort_t h) {
  return __uint_as_float((unsigned)h << 16);
}

// ---------------------------------------------------------------------------
// K0: split P into bf16 hi/lo.
__global__ __launch_bounds__(256) void pconv_kernel(
    const float* __restrict__ P, ushort_t* __restrict__ Phi,
    ushort_t* __restrict__ Plo)
{
  int idx = blockIdx.x * 1024 + threadIdx.x;
  #pragma unroll
  for (int p = 0; p < 4; ++p) {
    int i = idx + p * 256;
    float x = P[i];
    ushort_t h = bf16r(x);
    Phi[i] = h;
    Plo[i] = bf16r(x - ubf(h));
  }
}

// ---------------------------------------------------------------------------
// K1: feature map via MFMA. blocks 0..1023 -> q, 1024..2047 -> k.
// Epilogue stages bf16 results in LDS (aliased over the X tile) and emits
// coalesced 16B stores.
__global__ __launch_bounds__(256) void feat_mfma(
    const float* __restrict__ Q, const float* __restrict__ K,
    const ushort_t* __restrict__ Phi, const ushort_t* __restrict__ Plo,
    ushort_t* __restrict__ qp, ushort_t* __restrict__ E,
    unsigned int* __restrict__ kmax)
{
  __shared__ union {
    struct { ushort_t Xhi[64 * 72]; ushort_t Xlo[64 * 72]; } s;
    ushort_t outb[64 * 264];     // results [row][col], pitch 264
  } u;
  __shared__ float diagS[64];
  __shared__ float red[256];
  __shared__ float redm[4];

  int bid = blockIdx.x, tid = threadIdx.x;
  bool isK = bid >= 1024;
  const float* X = isK ? K : Q;
  size_t rowbase = (size_t)(isK ? bid - 1024 : bid) * 64;

  // stage X -> hi/lo bf16 (coalesced float4 reads)
  #pragma unroll
  for (int p = 0; p < 4; ++p) {
    int idx = tid + p * 256;
    int row = idx >> 4, c4 = idx & 15;
    float4 x = *(const float4*)&X[(rowbase + row) * 64 + c4 * 4];
    ushort4 h, l;
    h.x = bf16r(x.x); l.x = bf16r(x.x - ubf(h.x));
    h.y = bf16r(x.y); l.y = bf16r(x.y - ubf(h.y));
    h.z = bf16r(x.z); l.z = bf16r(x.z - ubf(h.z));
    h.w = bf16r(x.w); l.w = bf16r(x.w - ubf(h.w));
    *(ushort4*)&u.s.Xhi[row * 72 + c4 * 4] = h;
    *(ushort4*)&u.s.Xlo[row * 72 + c4 * 4] = l;
  }
  __syncthreads();

  // per-row diag = sumsq/16
  {
    int row = tid & 63, seg = tid >> 6;
    float s = 0.f;
    #pragma unroll
    for (int i2 = 0; i2 < 16; ++i2) {
      int o = row * 72 + seg * 16 + i2;
      float v = ubf(u.s.Xhi[o]) + ubf(u.s.Xlo[o]);
      s += v * v;
    }
    red[seg * 64 + row] = s;
  }
  __syncthreads();
  if (tid < 64)
    diagS[tid] = 0.0625f * (red[tid] + red[64 + tid] + red[128 + tid] + red[192 + tid]);

  int lane = tid & 63, wv = tid >> 6;
  int n15 = lane & 15, quad = lane >> 4;

  // A-fragments (hi/lo): all X reads complete before the barrier below,
  // after which u.outb may overwrite the X tile.
  bf16x8 ah[2], al[2];
  #pragma unroll
  for (int ks = 0; ks < 2; ++ks) {
    int off = (16 * wv + n15) * 72 + quad * 8 + 32 * ks;
    ah[ks] = *(const bf16x8*)&u.s.Xhi[off];
    al[ks] = *(const bf16x8*)&u.s.Xlo[off];
  }
  __syncthreads();   // diagS ready + all X reads done

  f32x4 acc[16];
  #pragma unroll
  for (int tc = 0; tc < 16; ++tc) {
    f32x4 a = {0.f, 0.f, 0.f, 0.f};
    #pragma unroll
    for (int ks = 0; ks < 2; ++ks) {
      int poff = (16 * tc + n15) * 64 + quad * 8 + 32 * ks;
      bf16x8 bh = *(const bf16x8*)&Phi[poff];
      bf16x8 bl = *(const bf16x8*)&Plo[poff];
      a = __builtin_amdgcn_mfma_f32_16x16x32_bf16(ah[ks], bh, a, 0, 0, 0);
      a = __builtin_amdgcn_mfma_f32_16x16x32_bf16(ah[ks], bl, a, 0, 0, 0);
      a = __builtin_amdgcn_mfma_f32_16x16x32_bf16(al[ks], bh, a, 0, 0, 0);
    }
    acc[tc] = a;
  }

  // C/D: row = 16*wv + quad*4 + r, col = 16*tc + n15
  float dg[4];
  #pragma unroll
  for (int r = 0; r < 4; ++r) dg[r] = diagS[16 * wv + quad * 4 + r];

  if (!isK) {
    float mx[4] = {-3.0e38f, -3.0e38f, -3.0e38f, -3.0e38f};
    #pragma unroll
    for (int tc = 0; tc < 16; ++tc)
      #pragma unroll
      for (int r = 0; r < 4; ++r) mx[r] = fmaxf(mx[r], acc[tc][r]);
    #pragma unroll
    for (int r = 0; r < 4; ++r) {
      #pragma unroll
      for (int s = 1; s < 16; s <<= 1) mx[r] = fmaxf(mx[r], __shfl_xor(mx[r], s, 64));
    }
    #pragma unroll
    for (int r = 0; r < 4; ++r) {
      int row = 16 * wv + quad * 4 + r;
      float sub = dg[r] + NORMIZER * mx[r];
      #pragma unroll
      for (int tc = 0; tc < 16; ++tc)
        u.outb[row * 264 + 16 * tc + n15] =
            bf16r(RATIO * (__expf(NORMIZER * acc[tc][r] - sub) + KEPS));
    }
  } else {
    float bm = -3.0e38f;
    #pragma unroll
    for (int r = 0; r < 4; ++r) {
      int row = 16 * wv + quad * 4 + r;
      #pragma unroll
      for (int tc = 0; tc < 16; ++tc) {
        float d = acc[tc][r];
        bm = fmaxf(bm, d);
        u.outb[row * 264 + 16 * tc + n15] = bf16r(__expf(NORMIZER * d - dg[r]));
      }
    }
    #pragma unroll
    for (int s = 1; s < 64; s <<= 1) bm = fmaxf(bm, __shfl_xor(bm, s, 64));
    if (lane == 0) redm[wv] = bm;
  }
  __syncthreads();

  // coalesced 16B stores
  ushort_t* dst = (isK ? E : qp) + rowbase * 256;
  #pragma unroll
  for (int p = 0; p < 8; ++p) {
    int f = p * 2048 + tid * 8;
    int row = f >> 8, col = f & 255;
    bf16x8 vv = *(const bf16x8*)&u.outb[row * 264 + col];
    *(bf16x8*)&dst[row * 256 + col] = vv;
  }

  if (isK && tid == 0) {
    float m4 = fmaxf(fmaxf(redm[0], redm[1]), fmaxf(redm[2], redm[3]));
    atomicMax(kmax, fenc(NORMIZER * m4));
  }
}

// ---------------------------------------------------------------------------
// K2: per-chunk sums. kp = c1*E + c0. S layout [bc][e][j].
__global__ __launch_bounds__(256) void chunksum_kernel(
    const ushort_t* __restrict__ E, const float* __restrict__ V,
    const unsigned int* __restrict__ kmax,
    ushort_t* __restrict__ S, float* __restrict__ Z)
{
  __shared__ float vs[4096];
  int bc = blockIdx.x, tid = threadIdx.x;
  float m = fdec(*kmax);
  float c1 = RATIO * __expf(-m);
  const float c0 = RATIO * KEPS;
  size_t vbase = (size_t)bc * 4096;
  #pragma unroll
  for (int p = 0; p < 16; ++p) vs[tid + p * 256] = V[vbase + tid + p * 256];
  __syncthreads();

  size_t kbase = (size_t)bc * 16384;
  float acc[64];
  #pragma unroll
  for (int e = 0; e < 64; ++e) acc[e] = 0.f;
  float z = 0.f;

  for (int pos = 0; pos < 64; ++pos) {
    float kj = c1 * ubf(E[kbase + (size_t)pos * 256 + tid]) + c0;
    z += kj;
    #pragma unroll
    for (int e4 = 0; e4 < 16; ++e4) {
      float4 vv = *(const float4*)&vs[pos * 64 + e4 * 4];
      acc[e4 * 4 + 0] += kj * vv.x;
      acc[e4 * 4 + 1] += kj * vv.y;
      acc[e4 * 4 + 2] += kj * vv.z;
      acc[e4 * 4 + 3] += kj * vv.w;
    }
  }
  #pragma unroll
  for (int e = 0; e < 64; ++e)
    S[kbase + (size_t)e * 256 + tid] = bf16r(acc[e]);
  Z[(size_t)bc * 256 + tid] = z;
}

// ---------------------------------------------------------------------------
// K3: exclusive prefix over 64 chunks per bh, in place. 8-deep prefetch.
__global__ __launch_bounds__(256) void prefix_kernel(ushort_t* __restrict__ S,
                                                     float* __restrict__ Z)
{
  int b = blockIdx.x;
  if (b < 1024) {
    int flat = b * 256 + threadIdx.x;
    int bh = flat >> 14;
    int idx = flat & 16383;
    size_t base = (size_t)bh * 1048576 + idx;
    float run = 0.f;
    for (int c0 = 0; c0 < 64; c0 += 8) {
      ushort_t t[8];
      #pragma unroll
      for (int u2 = 0; u2 < 8; ++u2)
        t[u2] = S[base + (size_t)(c0 + u2) * 16384];
      #pragma unroll
      for (int u2 = 0; u2 < 8; ++u2) {
        S[base + (size_t)(c0 + u2) * 16384] = bf16r(run);
        run += ubf(t[u2]);
      }
    }
  } else {
    int bh = b - 1024;
    int j = threadIdx.x;
    size_t base = (size_t)bh * 16384 + j;
    float run = 0.f;
    for (int c0 = 0; c0 < 64; c0 += 8) {
      float t[8];
      #pragma unroll
      for (int u2 = 0; u2 < 8; ++u2)
        t[u2] = Z[base + (size_t)(c0 + u2) * 256];
      #pragma unroll
      for (int u2 = 0; u2 < 8; ++u2) {
        Z[base + (size_t)(c0 + u2) * 256] = run;
        run += t[u2];
      }
    }
  }
}

// ---------------------------------------------------------------------------
// K4: fused MFMA scores + denominator + output. block = (bh,c).
__global__ __launch_bounds__(256) void fused_mfma(
    const ushort_t* __restrict__ qp, const ushort_t* __restrict__ E,
    const unsigned int* __restrict__ kmax, const float* __restrict__ Z,
    const ushort_t* __restrict__ S, const float* __restrict__ V,
    float* __restrict__ out)
{
  __shared__ ushort_t As[64 * 72];   // A_sc bf16, A-operand layout [i][t]
  __shared__ ushort_t Vt[64 * 72];   // V^T bf16 [e][t]
  __shared__ float zv[256];
  __shared__ float qsumS[64];
  __shared__ float dqS[64];

  int bc = blockIdx.x, tid = threadIdx.x;
  int lane = tid & 63, wv = tid >> 6;
  int n15 = lane & 15, quad = lane >> 4;
  float m = fdec(*kmax);
  float c1 = RATIO * __expf(-m);
  const float c0 = RATIO * KEPS;
  size_t base = (size_t)bc * 16384;

  zv[tid] = Z[(size_t)bc * 256 + tid] + AEPS;
  #pragma unroll
  for (int p = 0; p < 16; ++p) {
    int idx = tid + p * 256;
    int t = idx >> 6, e = idx & 63;
    Vt[e * 72 + t] = bf16r(V[(size_t)bc * 4096 + idx]);
  }
  __syncthreads();

  // Qp A-fragments: rows 16*wv + n15, held for both GEMMs
  bf16x8 aQ[8];
  #pragma unroll
  for (int ks = 0; ks < 8; ++ks)
    aQ[ks] = *(const bf16x8*)&qp[base + (size_t)(16 * wv + n15) * 256 + quad * 8 + 32 * ks];

  float qsum = 0.f, dq = 0.f;
  #pragma unroll
  for (int ks = 0; ks < 8; ++ks)
    #pragma unroll
    for (int j = 0; j < 8; ++j) {
      float qv = ubf((ushort_t)aQ[ks][j]);
      qsum += qv;
      dq += qv * zv[quad * 8 + 32 * ks + j];
    }
  qsum += __shfl_xor(qsum, 16, 64); qsum += __shfl_xor(qsum, 32, 64);
  dq   += __shfl_xor(dq, 16, 64);   dq   += __shfl_xor(dq, 32, 64);
  if (quad == 0) { qsumS[16 * wv + n15] = qsum; dqS[16 * wv + n15] = dq; }

  // ---- phase A: G = Qp * E^T ----
  float rs[4] = {0.f, 0.f, 0.f, 0.f};
  #pragma unroll
  for (int tc = 0; tc < 4; ++tc) {
    f32x4 g = {0.f, 0.f, 0.f, 0.f};
    #pragma unroll
    for (int ks = 0; ks < 8; ++ks) {
      bf16x8 b = *(const bf16x8*)&E[base + (size_t)(16 * tc + n15) * 256 + quad * 8 + 32 * ks];
      g = __builtin_amdgcn_mfma_f32_16x16x32_bf16(aQ[ks], b, g, 0, 0, 0);
    }
    #pragma unroll
    for (int r = 0; r < 4; ++r) {
      int i = 16 * wv + quad * 4 + r;
      int t = 16 * tc + n15;
      float val = (t <= i) ? (c1 * g[r] + c0 * qsumS[i]) : 0.f;
      As[i * 72 + t] = bf16r(val);
      rs[r] += val;
    }
  }

  float dinv[4];
  #pragma unroll
  for (int r = 0; r < 4; ++r) {
    float v = rs[r];
    #pragma unroll
    for (int s = 1; s < 16; s <<= 1) v += __shfl_xor(v, s, 64);
    int i = 16 * wv + quad * 4 + r;
    dinv[r] = 1.f / (dqS[i] + v);
  }

  // ---- phase C: out = [Qp | A_sc] * [Sp ; Vt] ----
  #pragma unroll
  for (int ec = 0; ec < 4; ++ec) {
    f32x4 o = {0.f, 0.f, 0.f, 0.f};
    #pragma unroll
    for (int ks = 0; ks < 8; ++ks) {
      bf16x8 b = *(const bf16x8*)&S[base + (size_t)(16 * ec + n15) * 256 + quad * 8 + 32 * ks];
      o = __builtin_amdgcn_mfma_f32_16x16x32_bf16(aQ[ks], b, o, 0, 0, 0);
    }
    #pragma unroll
    for (int ks = 0; ks < 2; ++ks) {
      bf16x8 a2 = *(const bf16x8*)&As[(16 * wv + n15) * 72 + quad * 8 + 32 * ks];
      bf16x8 b2 = *(const bf16x8*)&Vt[(16 * ec + n15) * 72 + quad * 8 + 32 * ks];
      o = __builtin_amdgcn_mfma_f32_16x16x32_bf16(a2, b2, o, 0, 0, 0);
    }
    #pragma unroll
    for (int r = 0; r < 4; ++r) {
      int i = 16 * wv + quad * 4 + r;
      out[(size_t)bc * 4096 + (size_t)i * 64 + 16 * ec + n15] = o[r] * dinv[r];
    }
  }
}

// ---------------------------------------------------------------------------
extern "C" void kernel_launch(void* const* d_in, const int* in_sizes, int n_in,
                              void* d_out, int out_size, void* d_ws, size_t ws_size,
                              hipStream_t stream)
{
  const float* q = (const float*)d_in[0];
  const float* k = (const float*)d_in[1];
  const float* v = (const float*)d_in[2];
  const float* P = (const float*)d_in[3];
  float* out = (float*)d_out;

  ushort_t* qp  = (ushort_t*)d_ws;
  ushort_t* E   = qp + 16777216;
  ushort_t* S   = E + 16777216;
  float*    Z   = (float*)(S + 16777216);
  ushort_t* Phi = (ushort_t*)(Z + 262144);
  ushort_t* Plo = Phi + 16384;
  unsigned int* kmax = (unsigned int*)(Plo + 16384);

  hipMemsetAsync(kmax, 0, 4, stream);
  pconv_kernel<<<16, 256, 0, stream>>>(P, Phi, Plo);
  feat_mfma<<<2048, 256, 0, stream>>>(q, k, Phi, Plo, qp, E, kmax);
  chunksum_kernel<<<1024, 256, 0, stream>>>(E, v, kmax, S, Z);
  prefix_kernel<<<1040, 256, 0, stream>>>(S, Z);
  fused_mfma<<<1024, 256, 0, stream>>>(qp, E, kmax, Z, S, v, out);
}